// Round 3
// baseline (675.160 us; speedup 1.0000x reference)
//
#include <hip/hip_runtime.h>

// CrossAttUnit V4: single fused kernel, all memory ops contiguous.
//   prep_kq: k,q -> FRAGMENT-MAJOR split-bf16 planes (128 KB ws, L2-resident),
//            so B-frag loads are wave-contiguous.
//   catt:    one block = one segment (64 tokens). Two 32-row phases:
//            stage Y[0:32)+Yhat[0:32) into LDS (coalesced float4, XOR-swizzled
//            granules) -> waves 0,1 compute yk rows, waves 2,3 compute yq rows
//            (split-bf16 MFMA, 3 products) -> repeat for rows [32:64).
//            Epilogue writes the split-bf16 pswz image into LDS (aliases the
//            dead staging buffer), then M = (1/8) yk@yq^T + in-register
//            softmax/colnorm (verbatim from the verified mix kernel).
// HBM traffic = 512 MB read + 64 MB write (roofline ~91 us). No pl2.
// Numerics bit-identical to V2/V3 (same RNE chain, product set, accum order).

#define H  256
#define D  64
#define L  64

typedef __attribute__((ext_vector_type(8))) short frag_b;   // 8 x bf16 (4 VGPR)
typedef __attribute__((ext_vector_type(4))) float frag_acc; // 4 x fp32

__device__ inline unsigned short f32_bf16_rne(float f) {
    unsigned u = __float_as_uint(f);
    u += 0x7FFFu + ((u >> 16) & 1u);   // round-to-nearest-even on sign-magnitude bits
    return (unsigned short)(u >> 16);
}
__device__ inline float bf16_f32(unsigned short h) {
    return __uint_as_float(((unsigned)h) << 16);
}

// Offset (in shorts) of (row,col) in a 64x64 bf16 plane; 16-B chunk XOR swizzle.
__device__ inline int pswz(int row, int col) {
    return (row << 6) + ((((col >> 3) ^ row) & 7) << 3) + (col & 7);
}

// ---- prep_kq: k,q -> fragment-major split-bf16 planes ----
// Layout (shorts): off(m,p,ks,kg,n,j) = m*32768 + p*16384 + ks*2048 + kg*512 + n*8 + j
// holding bf16 plane p of mat[h = ks*32+kg*8+j][d = n]. A wave's B-frag load
// (n = t*16+ln across lanes) is then 64 consecutive 16-B chunks = 1 KB contiguous.
__global__ void prep_kq(const float* __restrict__ k, const float* __restrict__ q,
                        unsigned short* __restrict__ kqF) {
    int tid = blockIdx.x * 256 + threadIdx.x;            // 0..32767
    int m   = (tid >= H * D) ? 1 : 0;
    const float* src = m ? q : k;
    int e = tid & (H * D - 1);
    int h = e >> 6, d = e & 63;                          // mat[h][d]
    float x = src[e];
    unsigned short hi = f32_bf16_rne(x);
    unsigned short lo = f32_bf16_rne(x - bf16_f32(hi));
    int ks = h >> 5, kg = (h >> 3) & 3, j = h & 7;
    int base = m * 32768 + ks * 2048 + kg * 512 + d * 8 + j;
    kqF[base]         = hi;                              // p=0 plane
    kqF[base + 16384] = lo;                              // p=1 plane
}

// Per-wave projection phase: 16 rows (rsel..rsel+15 of the 32-row buffer) x 64
// cols, K=256, split-bf16 (ah*bh + ah*bl + al*bh). A from swizzled LDS buffer,
// B from fragment-major global (L2-hot).
__device__ inline void compute_phase(const float* __restrict__ Abuf,
                                     const frag_b* __restrict__ fbh,
                                     const frag_b* __restrict__ fbl,
                                     int rsel, int ln, int kg, frag_acc acc[4]) {
    const frag_acc zf = {0.f, 0.f, 0.f, 0.f};
    #pragma unroll
    for (int t = 0; t < 4; t++) acc[t] = zf;
    const int rr = rsel + ln;
    const int s  = rr & 7;
    const float* rowp = Abuf + rr * 256;
    #pragma unroll
    for (int ks = 0; ks < 8; ks++) {
        const int c0 = ks * 8 + kg * 2;                  // logical 16-B granule
        float4 ua = *(const float4*)(rowp + ((c0 ^ s) * 4));
        float4 ub = *(const float4*)(rowp + (((c0 + 1) ^ s) * 4));
        float xs[8] = {ua.x, ua.y, ua.z, ua.w, ub.x, ub.y, ub.z, ub.w};
        frag_b ah, al;
        #pragma unroll
        for (int j = 0; j < 8; j++) {
            unsigned short hb = f32_bf16_rne(xs[j]);
            ah[j] = (short)hb;
            al[j] = (short)f32_bf16_rne(xs[j] - bf16_f32(hb));
        }
        #pragma unroll
        for (int t = 0; t < 4; t++) {
            frag_b bh = fbh[(ks * 4 + kg) * 64 + t * 16 + ln];
            frag_b bl = fbl[(ks * 4 + kg) * 64 + t * 16 + ln];
            acc[t] = __builtin_amdgcn_mfma_f32_16x16x32_bf16(ah, bh, acc[t], 0, 0, 0);
            acc[t] = __builtin_amdgcn_mfma_f32_16x16x32_bf16(ah, bl, acc[t], 0, 0, 0);
            acc[t] = __builtin_amdgcn_mfma_f32_16x16x32_bf16(al, bh, acc[t], 0, 0, 0);
        }
    }
}

__global__ __launch_bounds__(256, 2) void catt(
        const float* __restrict__ yhat, const float* __restrict__ y,
        const unsigned short* __restrict__ kqF, float* __restrict__ out) {
    // 64 KB: buf0 = Y rows (32x256 f32), buf1 = Yhat rows. After compute-2 the
    // split-bf16 pswz image (32 KB) aliases buf0; s_cs aliases buf1's start.
    __shared__ __align__(16) float lds_f[16384];

    const int b    = blockIdx.x;
    const int tid  = threadIdx.x;
    const int wave = tid >> 6;
    const int lane = tid & 63;
    const int ln   = lane & 15;
    const int kg   = lane >> 4;
    const int m    = wave >> 1;          // 0: yk (from Y), 1: yq (from Yhat)
    const int rsel = (wave & 1) * 16;    // row half within the 32-row buffer

    const frag_b* fb  = (const frag_b*)kqF;
    const frag_b* fbh = fb + (m * 2 + 0) * 2048;   // 2048 frags per plane
    const frag_b* fbl = fb + (m * 2 + 1) * 2048;

    // -------- staging assignment: thread -> (row, granule column) --------
    const int srow = tid >> 3;           // 0..31 (row within 32-row tile)
    const int sq   = tid & 7;            // granule column base
    const int sswz = srow & 7;
    const float* rpY0 = y    + ((size_t)(b * 64 + srow)) * 256;
    const float* rpQ0 = yhat + ((size_t)(b * 64 + srow)) * 256;

    // G0: load pair A (rows [0:32) of both mats), coalesced 128-B runs.
    float4 pf[2][8];
    #pragma unroll
    for (int i = 0; i < 8; i++) {
        pf[0][i] = *(const float4*)(rpY0 + (((sq + 8 * i) ^ sswz) * 4));
        pf[1][i] = *(const float4*)(rpQ0 + (((sq + 8 * i) ^ sswz) * 4));
    }
    // W0: write pair A into swizzled LDS positions.
    #pragma unroll
    for (int i = 0; i < 8; i++) {
        *(float4*)(lds_f +        srow * 256 + (sq + 8 * i) * 4) = pf[0][i];
        *(float4*)(lds_f + 8192 + srow * 256 + (sq + 8 * i) * 4) = pf[1][i];
    }
    // G1: issue pair B loads (rows [32:64)) now; they fly during compute-1.
    #pragma unroll
    for (int i = 0; i < 8; i++) {
        pf[0][i] = *(const float4*)(rpY0 + 32 * 256 + (((sq + 8 * i) ^ sswz) * 4));
        pf[1][i] = *(const float4*)(rpQ0 + 32 * 256 + (((sq + 8 * i) ^ sswz) * 4));
    }
    __syncthreads();                                            // (1) pair A visible

    // C1: rows [0:32) of this wave's matrix.
    frag_acc acc0[4];
    compute_phase(lds_f + m * 8192, fbh, fbl, rsel, ln, kg, acc0);
    __syncthreads();                                            // (2) buffers free

    // W1: write pair B.
    #pragma unroll
    for (int i = 0; i < 8; i++) {
        *(float4*)(lds_f +        srow * 256 + (sq + 8 * i) * 4) = pf[0][i];
        *(float4*)(lds_f + 8192 + srow * 256 + (sq + 8 * i) * 4) = pf[1][i];
    }
    __syncthreads();                                            // (3) pair B visible

    // C2: rows [32:64).
    frag_acc acc1[4];
    compute_phase(lds_f + m * 8192, fbh, fbl, rsel, ln, kg, acc1);
    __syncthreads();                                            // (4) before image alias

    // -------- epilogue: split-bf16 pswz image into LDS (aliases buf0) --------
    // C/D layout: col = lane&15, row = (lane>>4)*4 + i (m89/m91).
    {
        unsigned short* img = (unsigned short*)lds_f;
        unsigned short* mbH = img + m * 8192;   // [ykH|ykL|yqH|yqL] x 4096 shorts
        unsigned short* mbL = mbH + 4096;
        #pragma unroll
        for (int p = 0; p < 2; p++) {
            #pragma unroll
            for (int t = 0; t < 4; t++)
                #pragma unroll
                for (int i = 0; i < 4; i++) {
                    int r = p * 32 + rsel + kg * 4 + i;
                    int c = t * 16 + ln;
                    float x = p ? acc1[t][i] : acc0[t][i];
                    unsigned short hb = f32_bf16_rne(x);
                    int o = pswz(r, c);
                    mbH[o] = hb;
                    mbL[o] = f32_bf16_rne(x - bf16_f32(hb));
                }
        }
    }
    __syncthreads();                                            // (5) image visible

    // -------- M = (1/8) yk @ yq^T (verbatim from verified mix) --------
    const unsigned short* ykH = (const unsigned short*)lds_f;
    const unsigned short* ykL = ykH + 4096;
    const unsigned short* yqH = ykH + 8192;
    const unsigned short* yqL = ykH + 12288;

    const frag_acc zf = {0.f, 0.f, 0.f, 0.f};
    frag_acc mac[4];
    #pragma unroll
    for (int t = 0; t < 4; t++) mac[t] = zf;

    #pragma unroll
    for (int dk = 0; dk < 2; dk++) {
        const int colb = dk * 32 + kg * 8;
        frag_b ah = *(const frag_b*)(ykH + pswz(wave * 16 + ln, colb));
        frag_b al = *(const frag_b*)(ykL + pswz(wave * 16 + ln, colb));
        #pragma unroll
        for (int t = 0; t < 4; t++) {
            frag_b bh = *(const frag_b*)(yqH + pswz(t * 16 + ln, colb));
            frag_b bl = *(const frag_b*)(yqL + pswz(t * 16 + ln, colb));
            mac[t] = __builtin_amdgcn_mfma_f32_16x16x32_bf16(ah, bh, mac[t], 0, 0, 0);
            mac[t] = __builtin_amdgcn_mfma_f32_16x16x32_bf16(ah, bl, mac[t], 0, 0, 0);
            mac[t] = __builtin_amdgcn_mfma_f32_16x16x32_bf16(al, bh, mac[t], 0, 0, 0);
        }
    }
    __syncthreads();                                            // (6)

    // -------- softmax rows + column-normalize, in-register --------
    float* s_cs = lds_f + 8192;          // buf1 area (dead), 4 waves * 64 cols

    float a[4][4];
    float colpart[4] = {0.f, 0.f, 0.f, 0.f};
    #pragma unroll
    for (int i = 0; i < 4; i++) {
        float v0 = 0.125f * mac[0][i], v1 = 0.125f * mac[1][i];
        float v2 = 0.125f * mac[2][i], v3 = 0.125f * mac[3][i];
        float mx = fmaxf(fmaxf(v0, v1), fmaxf(v2, v3));
        #pragma unroll
        for (int off = 8; off >= 1; off >>= 1) mx = fmaxf(mx, __shfl_xor(mx, off, 64));
        float e0 = __expf(v0 - mx), e1 = __expf(v1 - mx);
        float e2 = __expf(v2 - mx), e3 = __expf(v3 - mx);
        float s = (e0 + e1) + (e2 + e3);
        #pragma unroll
        for (int off = 8; off >= 1; off >>= 1) s += __shfl_xor(s, off, 64);
        float rs = 1.f / s;
        a[0][i] = e0 * rs + 1e-6f; a[1][i] = e1 * rs + 1e-6f;
        a[2][i] = e2 * rs + 1e-6f; a[3][i] = e3 * rs + 1e-6f;
        colpart[0] += a[0][i]; colpart[1] += a[1][i];
        colpart[2] += a[2][i]; colpart[3] += a[3][i];
    }
    #pragma unroll
    for (int t = 0; t < 4; t++) {
        colpart[t] += __shfl_xor(colpart[t], 16, 64);
        colpart[t] += __shfl_xor(colpart[t], 32, 64);
    }
    s_cs[wave * 64 + kg * 16 + ln] = colpart[kg];
    __syncthreads();                                            // (7)

    float* ob = out + (size_t)b * (L * L);
    #pragma unroll
    for (int t = 0; t < 4; t++) {
        int c = t * 16 + ln;
        float inv = 1.f / (s_cs[c] + s_cs[64 + c] + s_cs[128 + c] + s_cs[192 + c]);
        #pragma unroll
        for (int i = 0; i < 4; i++)
            ob[(wave * 16 + kg * 4 + i) * 64 + c] = a[t][i] * inv;
    }
}

extern "C" void kernel_launch(void* const* d_in, const int* in_sizes, int n_in,
                              void* d_out, int out_size, void* d_ws, size_t ws_size,
                              hipStream_t stream) {
    const float* yhat = (const float*)d_in[0];
    const float* y    = (const float*)d_in[1];
    const float* k    = (const float*)d_in[2];
    const float* q    = (const float*)d_in[3];
    float* outp = (float*)d_out;
    unsigned short* kqF = (unsigned short*)d_ws;   // 65536 shorts = 128 KB

    const int N = in_sizes[0] / H;    // 262144
    const int B = N / L;              // 4096

    prep_kq<<<(2 * H * D) / 256, 256, 0, stream>>>(k, q, kqF);
    catt<<<B, 256, 0, stream>>>(yhat, y, kqF, outp);
}